// Round 7
// baseline (1170.241 us; speedup 1.0000x reference)
//
#include <hip/hip_runtime.h>

#define T_SEQ 769
#define N_SENT 768
#define E_IN 256
#define HID 128
#define G4 512
#define F_DIM 128

typedef _Float16 h2t __attribute__((ext_vector_type(2)));

#if __has_builtin(__builtin_amdgcn_fdot2)
#define FDOT2(a, b, c) __builtin_amdgcn_fdot2((a), (b), (c), false)
#else
#define FDOT2(a, b, c) fmaf((float)(a).x, (float)(b).x, fmaf((float)(a).y, (float)(b).y, (c)))
#endif

#if __has_builtin(__builtin_amdgcn_rcpf)
#define RCPF(x) __builtin_amdgcn_rcpf(x)
#else
#define RCPF(x) (1.0f / (x))
#endif

// v_exp_f32: D = 2^S0  (avoid __exp2f which collides with glibc math.h macros)
#if __has_builtin(__builtin_amdgcn_exp2f)
#define EXP2F(x) __builtin_amdgcn_exp2f(x)
#else
#define EXP2F(x) __builtin_exp2f(x)
#endif

// LDS-only barrier: waits lgkmcnt(0) then s_barrier; global prefetch loads
// stay in flight (vmcnt not drained).
#define LDS_BARRIER() asm volatile("s_waitcnt lgkmcnt(0)\n\ts_barrier" ::: "memory")

#define L2E 1.4426950408889634f

__device__ __forceinline__ float sigm(float x) {
    return 1.0f / (1.0f + __expf(-x));
}
__device__ __forceinline__ float tanh_f(float x) {
    return 1.0f - 2.0f / (1.0f + __expf(2.0f * x));
}
__device__ __forceinline__ h2t u2h(unsigned u) { return __builtin_bit_cast(h2t, u); }

// x = concat(sentence (768x256), root (1x256))
__global__ void build_x(const float* __restrict__ sent, const float* __restrict__ root,
                        float* __restrict__ x) {
    int row = blockIdx.x;
    int c = threadIdx.x;
    x[row * E_IN + c] = (row < N_SENT) ? sent[row * E_IN + c] : root[c];
}

// C[m,n] = sum_k A[ar(m),k] * B[n,k] + b0[n] + b1[n]
__global__ __launch_bounds__(256) void gemm_nt(
    const float* __restrict__ A, int lda, int M, int revA,
    const float* __restrict__ B, int ldb,
    const float* __restrict__ b0, const float* __restrict__ b1,
    float* __restrict__ C, int ldc, int K)
{
    __shared__ __align__(16) float As[16][68];
    __shared__ __align__(16) float Bs[16][68];
    int tid = threadIdx.x;
    int tx = tid & 15, ty = tid >> 4;
    int m0 = blockIdx.x * 64, n0 = blockIdx.y * 64;
    float acc[4][4] = {};
    int lrow = tid >> 2;
    int lk = (tid & 3) << 2;

    for (int k0 = 0; k0 < K; k0 += 16) {
        int m = m0 + lrow;
        float4 av = make_float4(0.f, 0.f, 0.f, 0.f);
        if (m < M) {
            int ar = revA ? (M - 1 - m) : m;
            av = *(const float4*)(A + (size_t)ar * lda + k0 + lk);
        }
        As[lk + 0][lrow] = av.x; As[lk + 1][lrow] = av.y;
        As[lk + 2][lrow] = av.z; As[lk + 3][lrow] = av.w;
        float4 bv = *(const float4*)(B + (size_t)(n0 + lrow) * ldb + k0 + lk);
        Bs[lk + 0][lrow] = bv.x; Bs[lk + 1][lrow] = bv.y;
        Bs[lk + 2][lrow] = bv.z; Bs[lk + 3][lrow] = bv.w;
        __syncthreads();
        #pragma unroll
        for (int k = 0; k < 16; ++k) {
            float4 a4 = *(const float4*)&As[k][ty * 4];
            float4 b4 = *(const float4*)&Bs[k][tx * 4];
            float aa[4] = {a4.x, a4.y, a4.z, a4.w};
            float bb[4] = {b4.x, b4.y, b4.z, b4.w};
            #pragma unroll
            for (int i = 0; i < 4; ++i)
                #pragma unroll
                for (int j = 0; j < 4; ++j)
                    acc[i][j] = fmaf(aa[i], bb[j], acc[i][j]);
        }
        __syncthreads();
    }
    float bias[4];
    #pragma unroll
    for (int j = 0; j < 4; ++j) {
        int n = n0 + tx * 4 + j;
        bias[j] = (b0 ? b0[n] : 0.f) + (b1 ? b1[n] : 0.f);
    }
    #pragma unroll
    for (int i = 0; i < 4; ++i) {
        int m = m0 + ty * 4 + i;
        if (m < M) {
            #pragma unroll
            for (int j = 0; j < 4; ++j)
                C[(size_t)m * ldc + n0 + tx * 4 + j] = acc[i][j] + bias[j];
        }
    }
}

// One BiLSTM layer. grid = 2 (dir), block = 512 (8 waves).
// Thread (u, q): all 4 gates of unit u over K-quarter q (32 of 128).
// Lane l: usub = l>>2, q = l&3; u = wave*16 + usub. Quad = one unit.
// LDS broadcast reads per step per CU: 8 waves x 4 ds_read_b128 = 32
// (vs 128 in the full-K layout) -- the LDS pipe was the R6 wall.
// Quad K-reduction via shfl_xor(1)/(2) butterflies (DPP, no LDS, no barrier).
// pre folded in pre-reduction: lane q fma's its gate-q pre into acc q.
__global__ __launch_bounds__(512, 2) void lstm_layer(
    const float* __restrict__ pre,
    const float* __restrict__ Whh,
    float* __restrict__ L)
{
    const int d = blockIdx.x;
    const int t = threadIdx.x;
    const int wv_id = t >> 6;
    const int l = t & 63;
    const int usub = l >> 2;
    const int q = l & 3;
    const int u = wv_id * 16 + usub;

    __shared__ __align__(16) unsigned short hb[2][HID];  // h as f16, dbuf

    // per-lane gate-selection masks for folding pre into the right acc
    const float m0 = (q == 0) ? 1.f : 0.f;
    const float m1 = (q == 1) ? 1.f : 0.f;
    const float m2 = (q == 2) ? 1.f : 0.f;
    const float m3 = (q == 3) ? 1.f : 0.f;

    // weights: gate g, unit u, K in [q*32, q*32+32) as 16 half2 -> 64 VGPRs
    h2t w[4][16];
    #pragma unroll
    for (int g = 0; g < 4; ++g) {
        const float* wr = Whh + ((size_t)d * G4 + g * HID + u) * HID + q * 32;
        #pragma unroll
        for (int k = 0; k < 16; ++k) {
            float2 v = *(const float2*)(wr + 2 * k);
            h2t p2v = {(_Float16)v.x, (_Float16)v.y};
            w[g][k] = p2v;
        }
    }

    if (t < HID) { hb[0][t] = 0; hb[1][t] = 0; }
    float c = 0.f;
    // this lane's pre element: gate q of unit u
    const float* pd = pre + (size_t)d * T_SEQ * G4 + q * HID + u;
    float p  = pd[0];        // step 0
    float p1 = pd[G4];       // step 1
    __syncthreads();

    for (int s = 0; s < T_SEQ; ++s) {
        // prefetch distance 2, rides across the LDS-only barrier
        float p2 = (s + 2 < T_SEQ) ? pd[(size_t)(s + 2) * G4] : 0.f;

        const uint4* hp = (const uint4*)&hb[s & 1][q * 32];
        float a0 = 0.f, a1 = 0.f, a2 = 0.f, a3 = 0.f;
        #pragma unroll
        for (int k = 0; k < 4; ++k) {
            uint4 hv = hp[k];  // 4 addresses/wave: 2-way bank alias = free
            a0 = FDOT2(w[0][k * 4 + 0], u2h(hv.x), a0);
            a1 = FDOT2(w[1][k * 4 + 0], u2h(hv.x), a1);
            a2 = FDOT2(w[2][k * 4 + 0], u2h(hv.x), a2);
            a3 = FDOT2(w[3][k * 4 + 0], u2h(hv.x), a3);
            a0 = FDOT2(w[0][k * 4 + 1], u2h(hv.y), a0);
            a1 = FDOT2(w[1][k * 4 + 1], u2h(hv.y), a1);
            a2 = FDOT2(w[2][k * 4 + 1], u2h(hv.y), a2);
            a3 = FDOT2(w[3][k * 4 + 1], u2h(hv.y), a3);
            a0 = FDOT2(w[0][k * 4 + 2], u2h(hv.z), a0);
            a1 = FDOT2(w[1][k * 4 + 2], u2h(hv.z), a1);
            a2 = FDOT2(w[2][k * 4 + 2], u2h(hv.z), a2);
            a3 = FDOT2(w[3][k * 4 + 2], u2h(hv.z), a3);
            a0 = FDOT2(w[0][k * 4 + 3], u2h(hv.w), a0);
            a1 = FDOT2(w[1][k * 4 + 3], u2h(hv.w), a1);
            a2 = FDOT2(w[2][k * 4 + 3], u2h(hv.w), a2);
            a3 = FDOT2(w[3][k * 4 + 3], u2h(hv.w), a3);
        }
        // fold this lane's pre into its own gate's partial (counted once)
        a0 = fmaf(m0, p, a0);
        a1 = fmaf(m1, p, a1);
        a2 = fmaf(m2, p, a2);
        a3 = fmaf(m3, p, a3);
        // quad butterfly: all 4 lanes end with full-K sums for all 4 gates
        a0 += __shfl_xor(a0, 1); a0 += __shfl_xor(a0, 2);
        a1 += __shfl_xor(a1, 1); a1 += __shfl_xor(a1, 2);
        a2 += __shfl_xor(a2, 1); a2 += __shfl_xor(a2, 2);
        a3 += __shfl_xor(a3, 1); a3 += __shfl_xor(a3, 2);

        float gi = RCPF(1.0f + EXP2F(-L2E * a0));
        float gf = RCPF(1.0f + EXP2F(-L2E * a1));
        float gg = fmaf(2.0f, RCPF(1.0f + EXP2F(-2.f * L2E * a2)), -1.0f);
        float go = RCPF(1.0f + EXP2F(-L2E * a3));
        c = fmaf(gf, c, gi * gg);  // uniform within quad
        float th = fmaf(2.0f, RCPF(1.0f + EXP2F(-2.f * L2E * c)), -1.0f);
        float h = go * th;
        if (q == 0) {
            int trow = d ? (N_SENT - s) : s;
            L[(size_t)trow * 256 + d * HID + u] = h;
            _Float16 hf = (_Float16)h;
            hb[(s + 1) & 1][u] = __builtin_bit_cast(unsigned short, hf);
        }
        p = p1; p1 = p2;
        LDS_BARRIER();
    }
}

// scores[i][j] = (i==j) ? -1e30 : b2 + sum_k w2[k]*tanh(Ap[i][k] + Bm[j][k])
__global__ __launch_bounds__(256) void scores_k(
    const float* __restrict__ Ap,   // [769][128]
    const float* __restrict__ Bm,   // [768][128]
    const float* __restrict__ w2,
    const float* __restrict__ b2,
    float* __restrict__ out)        // [769][768]
{
    __shared__ __align__(16) float Asl[32][132];
    __shared__ __align__(16) float Bsl[32][132];
    __shared__ __align__(16) float w2s[F_DIM];
    int tid = threadIdx.x;
    int i0 = blockIdx.x * 32, j0 = blockIdx.y * 32;

    for (int e = tid; e < 1024; e += 256) {
        int r = e >> 5;
        int qq = (e & 31) << 2;
        float4 av = (i0 + r < T_SEQ)
                        ? *(const float4*)(Ap + (size_t)(i0 + r) * F_DIM + qq)
                        : make_float4(0.f, 0.f, 0.f, 0.f);
        *(float4*)&Asl[r][qq] = av;
        float4 bv = *(const float4*)(Bm + (size_t)(j0 + r) * F_DIM + qq);
        *(float4*)&Bsl[r][qq] = bv;
    }
    if (tid < 32) {
        *(float4*)&w2s[tid * 4] = *(const float4*)(w2 + tid * 4);
    }
    __syncthreads();

    int tx = tid & 15, ty = tid >> 4;
    float s[2][2] = {};
    #pragma unroll 8
    for (int k4 = 0; k4 < F_DIM; k4 += 4) {
        float4 a0 = *(const float4*)&Asl[ty * 2][k4];
        float4 a1 = *(const float4*)&Asl[ty * 2 + 1][k4];
        float4 b0 = *(const float4*)&Bsl[tx * 2][k4];
        float4 b1v = *(const float4*)&Bsl[tx * 2 + 1][k4];
        float4 wv = *(const float4*)&w2s[k4];
        float aa[2][4] = {{a0.x, a0.y, a0.z, a0.w}, {a1.x, a1.y, a1.z, a1.w}};
        float bb[2][4] = {{b0.x, b0.y, b0.z, b0.w}, {b1v.x, b1v.y, b1v.z, b1v.w}};
        float ww[4] = {wv.x, wv.y, wv.z, wv.w};
        #pragma unroll
        for (int kk = 0; kk < 4; ++kk)
            #pragma unroll
            for (int ii = 0; ii < 2; ++ii)
                #pragma unroll
                for (int jj = 0; jj < 2; ++jj)
                    s[ii][jj] = fmaf(ww[kk], tanh_f(aa[ii][kk] + bb[jj][kk]), s[ii][jj]);
    }

    float bb2 = b2[0];
    #pragma unroll
    for (int ii = 0; ii < 2; ++ii) {
        int i = i0 + ty * 2 + ii;
        if (i < T_SEQ) {
            #pragma unroll
            for (int jj = 0; jj < 2; ++jj) {
                int j = j0 + tx * 2 + jj;
                out[(size_t)i * N_SENT + j] =
                    (i == j) ? -1.0e30f : (s[ii][jj] + bb2);
            }
        }
    }
}

extern "C" void kernel_launch(void* const* d_in, const int* in_sizes, int n_in,
                              void* d_out, int out_size, void* d_ws, size_t ws_size,
                              hipStream_t stream) {
    const float* sent = (const float*)d_in[0];
    const float* root = (const float*)d_in[2];
    const float* Wih  = (const float*)d_in[3];  // (2,2,512,256)
    const float* Whh  = (const float*)d_in[4];  // (2,2,512,128)
    const float* bih  = (const float*)d_in[5];  // (2,2,512)
    const float* bhh  = (const float*)d_in[6];  // (2,2,512)
    const float* W1   = (const float*)d_in[7];  // (128,512)
    const float* b1   = (const float*)d_in[8];  // (128)
    const float* w2   = (const float*)d_in[9];  // (128)
    const float* b2   = (const float*)d_in[10]; // (1)
    float* out = (float*)d_out;
    float* ws = (float*)d_ws;

    float* x   = ws;                       // 769*256
    float* pre = x + T_SEQ * E_IN;         // 2*769*512
    float* L0  = pre + 2 * T_SEQ * G4;     // 769*256
    float* L1  = L0 + T_SEQ * 256;         // 769*256
    float* Ap  = L1 + T_SEQ * 256;         // 769*128
    float* Bm  = Ap + T_SEQ * F_DIM;       // 768*128

    build_x<<<T_SEQ, E_IN, 0, stream>>>(sent, root, x);

    dim3 b256(256);
    dim3 gpre(13, 8);
    gemm_nt<<<gpre, b256, 0, stream>>>(x, E_IN, T_SEQ, 0,
                                       Wih, E_IN, bih, bhh, pre, G4, E_IN);
    gemm_nt<<<gpre, b256, 0, stream>>>(x, E_IN, T_SEQ, 1,
                                       Wih + (size_t)G4 * E_IN, E_IN,
                                       bih + G4, bhh + G4,
                                       pre + (size_t)T_SEQ * G4, G4, E_IN);
    lstm_layer<<<2, 512, 0, stream>>>(pre, Whh, L0);

    gemm_nt<<<gpre, b256, 0, stream>>>(L0, 256, T_SEQ, 0,
                                       Wih + (size_t)2 * G4 * E_IN, 256,
                                       bih + 2 * G4, bhh + 2 * G4, pre, G4, 256);
    gemm_nt<<<gpre, b256, 0, stream>>>(L0, 256, T_SEQ, 1,
                                       Wih + (size_t)3 * G4 * E_IN, 256,
                                       bih + 3 * G4, bhh + 3 * G4,
                                       pre + (size_t)T_SEQ * G4, G4, 256);
    lstm_layer<<<2, 512, 0, stream>>>(pre, Whh + (size_t)2 * G4 * HID, L1);

    gemm_nt<<<dim3(13, 2), b256, 0, stream>>>(L1, 256, T_SEQ, 0,
                                              W1, 512, b1, nullptr, Ap, F_DIM, 256);
    gemm_nt<<<dim3(12, 2), b256, 0, stream>>>(L1, 256, N_SENT, 0,
                                              W1 + 256, 512, nullptr, nullptr, Bm, F_DIM, 256);

    scores_k<<<dim3(25, 24), b256, 0, stream>>>(Ap, Bm, w2, b2, out);
}

// Round 8
// 1078.953 us; speedup vs baseline: 1.0846x; 1.0846x over previous
//
#include <hip/hip_runtime.h>

#define T_SEQ 769
#define N_SENT 768
#define E_IN 256
#define HID 128
#define G4 512
#define F_DIM 128

typedef _Float16 h2t __attribute__((ext_vector_type(2)));

#if __has_builtin(__builtin_amdgcn_fdot2)
#define FDOT2(a, b, c) __builtin_amdgcn_fdot2((a), (b), (c), false)
#else
#define FDOT2(a, b, c) fmaf((float)(a).x, (float)(b).x, fmaf((float)(a).y, (float)(b).y, (c)))
#endif

#if __has_builtin(__builtin_amdgcn_rcpf)
#define RCPF(x) __builtin_amdgcn_rcpf(x)
#else
#define RCPF(x) (1.0f / (x))
#endif

// v_exp_f32: D = 2^S0  (avoid __exp2f which collides with glibc math.h macros)
#if __has_builtin(__builtin_amdgcn_exp2f)
#define EXP2F(x) __builtin_amdgcn_exp2f(x)
#else
#define EXP2F(x) __builtin_exp2f(x)
#endif

// LDS-only barrier: waits lgkmcnt(0) then s_barrier; global prefetch loads
// stay in flight (vmcnt not drained).
#define LDS_BARRIER() asm volatile("s_waitcnt lgkmcnt(0)\n\ts_barrier" ::: "memory")

#define L2E 1.4426950408889634f

// Quad-lane reduction via DPP quad_perm (VALU pipe, ~2cy) instead of
// __shfl_xor (ds_swizzle on the LDS pipe, ~60-120cy latency each — this
// was R7's regression: 8 swizzles, 2 dependent levels, on the critical path).
#if __has_builtin(__builtin_amdgcn_update_dpp)
__device__ __forceinline__ float quad_reduce_add(float x) {
    // xor 1: quad_perm[1,0,3,2] = 0xB1
    int v1 = __builtin_amdgcn_update_dpp(0, __builtin_bit_cast(int, x), 0xB1, 0xF, 0xF, true);
    x += __builtin_bit_cast(float, v1);
    // xor 2: quad_perm[2,3,0,1] = 0x4E
    int v2 = __builtin_amdgcn_update_dpp(0, __builtin_bit_cast(int, x), 0x4E, 0xF, 0xF, true);
    x += __builtin_bit_cast(float, v2);
    return x;
}
#else
__device__ __forceinline__ float quad_reduce_add(float x) {
    x += __shfl_xor(x, 1);
    x += __shfl_xor(x, 2);
    return x;
}
#endif

__device__ __forceinline__ float sigm(float x) {
    return 1.0f / (1.0f + __expf(-x));
}
__device__ __forceinline__ float tanh_f(float x) {
    return 1.0f - 2.0f / (1.0f + __expf(2.0f * x));
}
__device__ __forceinline__ h2t u2h(unsigned u) { return __builtin_bit_cast(h2t, u); }

// x = concat(sentence (768x256), root (1x256))
__global__ void build_x(const float* __restrict__ sent, const float* __restrict__ root,
                        float* __restrict__ x) {
    int row = blockIdx.x;
    int c = threadIdx.x;
    x[row * E_IN + c] = (row < N_SENT) ? sent[row * E_IN + c] : root[c];
}

// C[m,n] = sum_k A[ar(m),k] * B[n,k] + b0[n] + b1[n]
__global__ __launch_bounds__(256) void gemm_nt(
    const float* __restrict__ A, int lda, int M, int revA,
    const float* __restrict__ B, int ldb,
    const float* __restrict__ b0, const float* __restrict__ b1,
    float* __restrict__ C, int ldc, int K)
{
    __shared__ __align__(16) float As[16][68];
    __shared__ __align__(16) float Bs[16][68];
    int tid = threadIdx.x;
    int tx = tid & 15, ty = tid >> 4;
    int m0 = blockIdx.x * 64, n0 = blockIdx.y * 64;
    float acc[4][4] = {};
    int lrow = tid >> 2;
    int lk = (tid & 3) << 2;

    for (int k0 = 0; k0 < K; k0 += 16) {
        int m = m0 + lrow;
        float4 av = make_float4(0.f, 0.f, 0.f, 0.f);
        if (m < M) {
            int ar = revA ? (M - 1 - m) : m;
            av = *(const float4*)(A + (size_t)ar * lda + k0 + lk);
        }
        As[lk + 0][lrow] = av.x; As[lk + 1][lrow] = av.y;
        As[lk + 2][lrow] = av.z; As[lk + 3][lrow] = av.w;
        float4 bv = *(const float4*)(B + (size_t)(n0 + lrow) * ldb + k0 + lk);
        Bs[lk + 0][lrow] = bv.x; Bs[lk + 1][lrow] = bv.y;
        Bs[lk + 2][lrow] = bv.z; Bs[lk + 3][lrow] = bv.w;
        __syncthreads();
        #pragma unroll
        for (int k = 0; k < 16; ++k) {
            float4 a4 = *(const float4*)&As[k][ty * 4];
            float4 b4 = *(const float4*)&Bs[k][tx * 4];
            float aa[4] = {a4.x, a4.y, a4.z, a4.w};
            float bb[4] = {b4.x, b4.y, b4.z, b4.w};
            #pragma unroll
            for (int i = 0; i < 4; ++i)
                #pragma unroll
                for (int j = 0; j < 4; ++j)
                    acc[i][j] = fmaf(aa[i], bb[j], acc[i][j]);
        }
        __syncthreads();
    }
    float bias[4];
    #pragma unroll
    for (int j = 0; j < 4; ++j) {
        int n = n0 + tx * 4 + j;
        bias[j] = (b0 ? b0[n] : 0.f) + (b1 ? b1[n] : 0.f);
    }
    #pragma unroll
    for (int i = 0; i < 4; ++i) {
        int m = m0 + ty * 4 + i;
        if (m < M) {
            #pragma unroll
            for (int j = 0; j < 4; ++j)
                C[(size_t)m * ldc + n0 + tx * 4 + j] = acc[i][j] + bias[j];
        }
    }
}

// One BiLSTM layer. grid = 2 (dir), block = 512 (8 waves).
// Thread (u, q): all 4 gates of unit u over K-quarter q (32 of 128).
// Lane l: usub = l>>2, q = l&3; u = wave*16 + usub. Quad = one unit.
// Quad K-reduction via DPP quad_perm adds (VALU, no LDS pipe, no barrier).
// pre folded pre-reduction: lane q fma's its gate-q pre into acc q.
// One LDS-only barrier per step; pre prefetch (distance 2) rides across it.
__global__ __launch_bounds__(512, 2) void lstm_layer(
    const float* __restrict__ pre,
    const float* __restrict__ Whh,
    float* __restrict__ L)
{
    const int d = blockIdx.x;
    const int t = threadIdx.x;
    const int wv_id = t >> 6;
    const int l = t & 63;
    const int usub = l >> 2;
    const int q = l & 3;
    const int u = wv_id * 16 + usub;

    __shared__ __align__(16) unsigned short hb[2][HID];  // h as f16, dbuf

    // per-lane gate-selection masks for folding pre into the right acc
    const float m0 = (q == 0) ? 1.f : 0.f;
    const float m1 = (q == 1) ? 1.f : 0.f;
    const float m2 = (q == 2) ? 1.f : 0.f;
    const float m3 = (q == 3) ? 1.f : 0.f;

    // weights: gate g, unit u, K in [q*32, q*32+32) as 16 half2 -> 64 VGPRs
    h2t w[4][16];
    #pragma unroll
    for (int g = 0; g < 4; ++g) {
        const float* wr = Whh + ((size_t)d * G4 + g * HID + u) * HID + q * 32;
        #pragma unroll
        for (int k = 0; k < 16; ++k) {
            float2 v = *(const float2*)(wr + 2 * k);
            h2t p2v = {(_Float16)v.x, (_Float16)v.y};
            w[g][k] = p2v;
        }
    }

    if (t < HID) { hb[0][t] = 0; hb[1][t] = 0; }
    float c = 0.f;
    // this lane's pre element: gate q of unit u
    const float* pd = pre + (size_t)d * T_SEQ * G4 + q * HID + u;
    float p  = pd[0];        // step 0
    float p1 = pd[G4];       // step 1
    __syncthreads();

    for (int s = 0; s < T_SEQ; ++s) {
        // prefetch distance 2, rides across the LDS-only barrier
        float p2 = (s + 2 < T_SEQ) ? pd[(size_t)(s + 2) * G4] : 0.f;

        const uint4* hp = (const uint4*)&hb[s & 1][q * 32];
        float a0 = 0.f, a1 = 0.f, a2 = 0.f, a3 = 0.f;
        #pragma unroll
        for (int k = 0; k < 4; ++k) {
            uint4 hv = hp[k];  // 4 addresses/wave: 2-way bank alias = free
            a0 = FDOT2(w[0][k * 4 + 0], u2h(hv.x), a0);
            a1 = FDOT2(w[1][k * 4 + 0], u2h(hv.x), a1);
            a2 = FDOT2(w[2][k * 4 + 0], u2h(hv.x), a2);
            a3 = FDOT2(w[3][k * 4 + 0], u2h(hv.x), a3);
            a0 = FDOT2(w[0][k * 4 + 1], u2h(hv.y), a0);
            a1 = FDOT2(w[1][k * 4 + 1], u2h(hv.y), a1);
            a2 = FDOT2(w[2][k * 4 + 1], u2h(hv.y), a2);
            a3 = FDOT2(w[3][k * 4 + 1], u2h(hv.y), a3);
            a0 = FDOT2(w[0][k * 4 + 2], u2h(hv.z), a0);
            a1 = FDOT2(w[1][k * 4 + 2], u2h(hv.z), a1);
            a2 = FDOT2(w[2][k * 4 + 2], u2h(hv.z), a2);
            a3 = FDOT2(w[3][k * 4 + 2], u2h(hv.z), a3);
            a0 = FDOT2(w[0][k * 4 + 3], u2h(hv.w), a0);
            a1 = FDOT2(w[1][k * 4 + 3], u2h(hv.w), a1);
            a2 = FDOT2(w[2][k * 4 + 3], u2h(hv.w), a2);
            a3 = FDOT2(w[3][k * 4 + 3], u2h(hv.w), a3);
        }
        // fold this lane's pre into its own gate's partial (counted once)
        a0 = fmaf(m0, p, a0);
        a1 = fmaf(m1, p, a1);
        a2 = fmaf(m2, p, a2);
        a3 = fmaf(m3, p, a3);
        // quad reduction on the VALU pipe (DPP), all 4 lanes get full sums
        a0 = quad_reduce_add(a0);
        a1 = quad_reduce_add(a1);
        a2 = quad_reduce_add(a2);
        a3 = quad_reduce_add(a3);

        float gi = RCPF(1.0f + EXP2F(-L2E * a0));
        float gf = RCPF(1.0f + EXP2F(-L2E * a1));
        float gg = fmaf(2.0f, RCPF(1.0f + EXP2F(-2.f * L2E * a2)), -1.0f);
        float go = RCPF(1.0f + EXP2F(-L2E * a3));
        c = fmaf(gf, c, gi * gg);  // uniform within quad
        float th = fmaf(2.0f, RCPF(1.0f + EXP2F(-2.f * L2E * c)), -1.0f);
        float h = go * th;
        if (q == 0) {
            int trow = d ? (N_SENT - s) : s;
            L[(size_t)trow * 256 + d * HID + u] = h;
            _Float16 hf = (_Float16)h;
            hb[(s + 1) & 1][u] = __builtin_bit_cast(unsigned short, hf);
        }
        p = p1; p1 = p2;
        LDS_BARRIER();
    }
}

// scores[i][j] = (i==j) ? -1e30 : b2 + sum_k w2[k]*tanh(Ap[i][k] + Bm[j][k])
__global__ __launch_bounds__(256) void scores_k(
    const float* __restrict__ Ap,   // [769][128]
    const float* __restrict__ Bm,   // [768][128]
    const float* __restrict__ w2,
    const float* __restrict__ b2,
    float* __restrict__ out)        // [769][768]
{
    __shared__ __align__(16) float Asl[32][132];
    __shared__ __align__(16) float Bsl[32][132];
    __shared__ __align__(16) float w2s[F_DIM];
    int tid = threadIdx.x;
    int i0 = blockIdx.x * 32, j0 = blockIdx.y * 32;

    for (int e = tid; e < 1024; e += 256) {
        int r = e >> 5;
        int qq = (e & 31) << 2;
        float4 av = (i0 + r < T_SEQ)
                        ? *(const float4*)(Ap + (size_t)(i0 + r) * F_DIM + qq)
                        : make_float4(0.f, 0.f, 0.f, 0.f);
        *(float4*)&Asl[r][qq] = av;
        float4 bv = *(const float4*)(Bm + (size_t)(j0 + r) * F_DIM + qq);
        *(float4*)&Bsl[r][qq] = bv;
    }
    if (tid < 32) {
        *(float4*)&w2s[tid * 4] = *(const float4*)(w2 + tid * 4);
    }
    __syncthreads();

    int tx = tid & 15, ty = tid >> 4;
    float s[2][2] = {};
    #pragma unroll 8
    for (int k4 = 0; k4 < F_DIM; k4 += 4) {
        float4 a0 = *(const float4*)&Asl[ty * 2][k4];
        float4 a1 = *(const float4*)&Asl[ty * 2 + 1][k4];
        float4 b0 = *(const float4*)&Bsl[tx * 2][k4];
        float4 b1v = *(const float4*)&Bsl[tx * 2 + 1][k4];
        float4 wv = *(const float4*)&w2s[k4];
        float aa[2][4] = {{a0.x, a0.y, a0.z, a0.w}, {a1.x, a1.y, a1.z, a1.w}};
        float bb[2][4] = {{b0.x, b0.y, b0.z, b0.w}, {b1v.x, b1v.y, b1v.z, b1v.w}};
        float ww[4] = {wv.x, wv.y, wv.z, wv.w};
        #pragma unroll
        for (int kk = 0; kk < 4; ++kk)
            #pragma unroll
            for (int ii = 0; ii < 2; ++ii)
                #pragma unroll
                for (int jj = 0; jj < 2; ++jj)
                    s[ii][jj] = fmaf(ww[kk], tanh_f(aa[ii][kk] + bb[jj][kk]), s[ii][jj]);
    }

    float bb2 = b2[0];
    #pragma unroll
    for (int ii = 0; ii < 2; ++ii) {
        int i = i0 + ty * 2 + ii;
        if (i < T_SEQ) {
            #pragma unroll
            for (int jj = 0; jj < 2; ++jj) {
                int j = j0 + tx * 2 + jj;
                out[(size_t)i * N_SENT + j] =
                    (i == j) ? -1.0e30f : (s[ii][jj] + bb2);
            }
        }
    }
}

extern "C" void kernel_launch(void* const* d_in, const int* in_sizes, int n_in,
                              void* d_out, int out_size, void* d_ws, size_t ws_size,
                              hipStream_t stream) {
    const float* sent = (const float*)d_in[0];
    const float* root = (const float*)d_in[2];
    const float* Wih  = (const float*)d_in[3];  // (2,2,512,256)
    const float* Whh  = (const float*)d_in[4];  // (2,2,512,128)
    const float* bih  = (const float*)d_in[5];  // (2,2,512)
    const float* bhh  = (const float*)d_in[6];  // (2,2,512)
    const float* W1   = (const float*)d_in[7];  // (128,512)
    const float* b1   = (const float*)d_in[8];  // (128)
    const float* w2   = (const float*)d_in[9];  // (128)
    const float* b2   = (const float*)d_in[10]; // (1)
    float* out = (float*)d_out;
    float* ws = (float*)d_ws;

    float* x   = ws;                       // 769*256
    float* pre = x + T_SEQ * E_IN;         // 2*769*512
    float* L0  = pre + 2 * T_SEQ * G4;     // 769*256
    float* L1  = L0 + T_SEQ * 256;         // 769*256
    float* Ap  = L1 + T_SEQ * 256;         // 769*128
    float* Bm  = Ap + T_SEQ * F_DIM;       // 768*128

    build_x<<<T_SEQ, E_IN, 0, stream>>>(sent, root, x);

    dim3 b256(256);
    dim3 gpre(13, 8);
    gemm_nt<<<gpre, b256, 0, stream>>>(x, E_IN, T_SEQ, 0,
                                       Wih, E_IN, bih, bhh, pre, G4, E_IN);
    gemm_nt<<<gpre, b256, 0, stream>>>(x, E_IN, T_SEQ, 1,
                                       Wih + (size_t)G4 * E_IN, E_IN,
                                       bih + G4, bhh + G4,
                                       pre + (size_t)T_SEQ * G4, G4, E_IN);
    lstm_layer<<<2, 512, 0, stream>>>(pre, Whh, L0);

    gemm_nt<<<gpre, b256, 0, stream>>>(L0, 256, T_SEQ, 0,
                                       Wih + (size_t)2 * G4 * E_IN, 256,
                                       bih + 2 * G4, bhh + 2 * G4, pre, G4, 256);
    gemm_nt<<<gpre, b256, 0, stream>>>(L0, 256, T_SEQ, 1,
                                       Wih + (size_t)3 * G4 * E_IN, 256,
                                       bih + 3 * G4, bhh + 3 * G4,
                                       pre + (size_t)T_SEQ * G4, G4, 256);
    lstm_layer<<<2, 512, 0, stream>>>(pre, Whh + (size_t)2 * G4 * HID, L1);

    gemm_nt<<<dim3(13, 2), b256, 0, stream>>>(L1, 256, T_SEQ, 0,
                                              W1, 512, b1, nullptr, Ap, F_DIM, 256);
    gemm_nt<<<dim3(12, 2), b256, 0, stream>>>(L1, 256, N_SENT, 0,
                                              W1 + 256, 512, nullptr, nullptr, Bm, F_DIM, 256);

    scores_k<<<dim3(25, 24), b256, 0, stream>>>(Ap, Bm, w2, b2, out);
}

// Round 10
// 1010.932 us; speedup vs baseline: 1.1576x; 1.0673x over previous
//
#include <hip/hip_runtime.h>

#define T_SEQ 769
#define N_SENT 768
#define E_IN 256
#define HID 128
#define G4 512
#define F_DIM 128

typedef _Float16 h2t __attribute__((ext_vector_type(2)));

#if __has_builtin(__builtin_amdgcn_fdot2)
#define FDOT2(a, b, c) __builtin_amdgcn_fdot2((a), (b), (c), false)
#else
#define FDOT2(a, b, c) fmaf((float)(a).x, (float)(b).x, fmaf((float)(a).y, (float)(b).y, (c)))
#endif

#if __has_builtin(__builtin_amdgcn_rcpf)
#define RCPF(x) __builtin_amdgcn_rcpf(x)
#else
#define RCPF(x) (1.0f / (x))
#endif

#if __has_builtin(__builtin_amdgcn_exp2f)
#define EXP2F(x) __builtin_amdgcn_exp2f(x)
#else
#define EXP2F(x) __builtin_exp2f(x)
#endif

// LDS-only barrier: waits lgkmcnt(0) then s_barrier; global prefetch loads
// stay in flight (vmcnt not drained).
#define LDS_BARRIER() asm volatile("s_waitcnt lgkmcnt(0)\n\ts_barrier" ::: "memory")

#define L2E 1.4426950408889634f

// DPP quad_perm helpers (VALU pipe, ~2cy; NOT ds_swizzle).
// dpp_ctrl must be an immediate -> template parameter.
template <int CODE>
__device__ __forceinline__ float dpp_qperm(float x) {
    int v = __builtin_amdgcn_update_dpp(0, __builtin_bit_cast(int, x), CODE, 0xF, 0xF, true);
    return __builtin_bit_cast(float, v);
}
#define QP_XOR1 0xB1  // [1,0,3,2]
#define QP_XOR2 0x4E  // [2,3,0,1]
#define QP_B0   0x00  // [0,0,0,0]
#define QP_B1   0x55  // [1,1,1,1]
#define QP_B2   0xAA  // [2,2,2,2]
#define QP_B3   0xFF  // [3,3,3,3]

__device__ __forceinline__ float tanh_f(float x) {
    return 1.0f - 2.0f / (1.0f + __expf(2.0f * x));
}
__device__ __forceinline__ h2t u2h(unsigned u) { return __builtin_bit_cast(h2t, u); }

// x = concat(sentence (768x256), root (1x256))
__global__ void build_x(const float* __restrict__ sent, const float* __restrict__ root,
                        float* __restrict__ x) {
    int row = blockIdx.x;
    int c = threadIdx.x;
    x[row * E_IN + c] = (row < N_SENT) ? sent[row * E_IN + c] : root[c];
}

// C[m,n] = sum_k A[ar(m),k] * B[n,k] + b0[n] + b1[n]
__global__ __launch_bounds__(256) void gemm_nt(
    const float* __restrict__ A, int lda, int M, int revA,
    const float* __restrict__ B, int ldb,
    const float* __restrict__ b0, const float* __restrict__ b1,
    float* __restrict__ C, int ldc, int K)
{
    __shared__ __align__(16) float As[16][68];
    __shared__ __align__(16) float Bs[16][68];
    int tid = threadIdx.x;
    int tx = tid & 15, ty = tid >> 4;
    int m0 = blockIdx.x * 64, n0 = blockIdx.y * 64;
    float acc[4][4] = {};
    int lrow = tid >> 2;
    int lk = (tid & 3) << 2;

    for (int k0 = 0; k0 < K; k0 += 16) {
        int m = m0 + lrow;
        float4 av = make_float4(0.f, 0.f, 0.f, 0.f);
        if (m < M) {
            int ar = revA ? (M - 1 - m) : m;
            av = *(const float4*)(A + (size_t)ar * lda + k0 + lk);
        }
        As[lk + 0][lrow] = av.x; As[lk + 1][lrow] = av.y;
        As[lk + 2][lrow] = av.z; As[lk + 3][lrow] = av.w;
        float4 bv = *(const float4*)(B + (size_t)(n0 + lrow) * ldb + k0 + lk);
        Bs[lk + 0][lrow] = bv.x; Bs[lk + 1][lrow] = bv.y;
        Bs[lk + 2][lrow] = bv.z; Bs[lk + 3][lrow] = bv.w;
        __syncthreads();
        #pragma unroll
        for (int k = 0; k < 16; ++k) {
            float4 a4 = *(const float4*)&As[k][ty * 4];
            float4 b4 = *(const float4*)&Bs[k][tx * 4];
            float aa[4] = {a4.x, a4.y, a4.z, a4.w};
            float bb[4] = {b4.x, b4.y, b4.z, b4.w};
            #pragma unroll
            for (int i = 0; i < 4; ++i)
                #pragma unroll
                for (int j = 0; j < 4; ++j)
                    acc[i][j] = fmaf(aa[i], bb[j], acc[i][j]);
        }
        __syncthreads();
    }
    float bias[4];
    #pragma unroll
    for (int j = 0; j < 4; ++j) {
        int n = n0 + tx * 4 + j;
        bias[j] = (b0 ? b0[n] : 0.f) + (b1 ? b1[n] : 0.f);
    }
    #pragma unroll
    for (int i = 0; i < 4; ++i) {
        int m = m0 + ty * 4 + i;
        if (m < M) {
            #pragma unroll
            for (int j = 0; j < 4; ++j)
                C[(size_t)m * ldc + n0 + tx * 4 + j] = acc[i][j] + bias[j];
        }
    }
}

// One BiLSTM layer. grid = 2 (dir), block = 512 (8 waves).
// Thread (u, q): all 4 gates of unit u over K-quarter q (32 of 128).
// After dots, a transpose-reduce (cndmask + DPP xor1/xor2) leaves lane q
// holding the FULL sum of gate q only; lane q applies only its own gate's
// activation (per-lane constants); 4 DPP quad-broadcasts gather i,f,g,o.
// waves_per_eu(2,2): caps occupancy at what we use so the allocator keeps
// the 64-VGPR weight array in arch VGPRs (R2-R8 showed VGPR_Count ~68 ->
// weights were in AGPRs, likely paying a mov per dot2).
__global__ __launch_bounds__(512)
__attribute__((amdgpu_waves_per_eu(2, 2)))
void lstm_layer(
    const float* __restrict__ pre,
    const float* __restrict__ Whh,
    float* __restrict__ L)
{
    const int d = blockIdx.x;
    const int t = threadIdx.x;
    const int wv_id = t >> 6;
    const int l = t & 63;
    const int usub = l >> 2;
    const int q = l & 3;
    const int u = wv_id * 16 + usub;

    __shared__ __align__(16) unsigned short hb[2][HID];  // h as f16, dbuf

    const bool q1 = (q & 1) != 0;
    const bool q2 = (q & 2) != 0;
    // own-gate activation constants: gates 0,1,3 sigmoid; gate 2 tanh
    const float Aa = (q == 2) ? 2.0f : 1.0f;
    const float Bb = (q == 2) ? (-2.0f * L2E) : (-L2E);
    const float Cc = (q == 2) ? -1.0f : 0.0f;

    // weights: gate g, unit u, K in [q*32, q*32+32) as 16 half2 -> 64 VGPRs
    h2t w[4][16];
    #pragma unroll
    for (int g = 0; g < 4; ++g) {
        const float* wr = Whh + ((size_t)d * G4 + g * HID + u) * HID + q * 32;
        #pragma unroll
        for (int k = 0; k < 16; ++k) {
            float2 v = *(const float2*)(wr + 2 * k);
            h2t p2v = {(_Float16)v.x, (_Float16)v.y};
            w[g][k] = p2v;
        }
    }

    if (t < HID) { hb[0][t] = 0; hb[1][t] = 0; }
    float c = 0.f;
    // this lane's pre element: gate q of unit u
    const float* pd = pre + (size_t)d * T_SEQ * G4 + q * HID + u;
    float p  = pd[0];        // step 0
    float p1 = pd[G4];       // step 1
    __syncthreads();

    for (int s = 0; s < T_SEQ; ++s) {
        // prefetch distance 2, rides across the LDS-only barrier
        float p2 = (s + 2 < T_SEQ) ? pd[(size_t)(s + 2) * G4] : 0.f;

        const uint4* hp = (const uint4*)&hb[s & 1][q * 32];
        float a0 = 0.f, a1 = 0.f, a2 = 0.f, a3 = 0.f;
        #pragma unroll
        for (int k = 0; k < 4; ++k) {
            uint4 hv = hp[k];  // 4 addresses/wave: 2-way bank alias = free
            a0 = FDOT2(w[0][k * 4 + 0], u2h(hv.x), a0);
            a1 = FDOT2(w[1][k * 4 + 0], u2h(hv.x), a1);
            a2 = FDOT2(w[2][k * 4 + 0], u2h(hv.x), a2);
            a3 = FDOT2(w[3][k * 4 + 0], u2h(hv.x), a3);
            a0 = FDOT2(w[0][k * 4 + 1], u2h(hv.y), a0);
            a1 = FDOT2(w[1][k * 4 + 1], u2h(hv.y), a1);
            a2 = FDOT2(w[2][k * 4 + 1], u2h(hv.y), a2);
            a3 = FDOT2(w[3][k * 4 + 1], u2h(hv.y), a3);
            a0 = FDOT2(w[0][k * 4 + 2], u2h(hv.z), a0);
            a1 = FDOT2(w[1][k * 4 + 2], u2h(hv.z), a1);
            a2 = FDOT2(w[2][k * 4 + 2], u2h(hv.z), a2);
            a3 = FDOT2(w[3][k * 4 + 2], u2h(hv.z), a3);
            a0 = FDOT2(w[0][k * 4 + 3], u2h(hv.w), a0);
            a1 = FDOT2(w[1][k * 4 + 3], u2h(hv.w), a1);
            a2 = FDOT2(w[2][k * 4 + 3], u2h(hv.w), a2);
            a3 = FDOT2(w[3][k * 4 + 3], u2h(hv.w), a3);
        }
        // transpose-reduce: lane q ends with FULL sum of gate q.
        // level 1 (xor1 pairs): gates {0,1} and {2,3}
        float sel01 = q1 ? a1 : a0;
        float alt01 = q1 ? a0 : a1;
        sel01 += dpp_qperm<QP_XOR1>(alt01);
        float sel23 = q1 ? a3 : a2;
        float alt23 = q1 ? a2 : a3;
        sel23 += dpp_qperm<QP_XOR1>(alt23);
        // level 2 (xor2)
        float selq = q2 ? sel23 : sel01;
        float altq = q2 ? sel01 : sel23;
        selq += dpp_qperm<QP_XOR2>(altq);
        float xg = selq + p;  // own pre folded once

        // own-gate activation only (per-lane constants)
        float r = fmaf(Aa, RCPF(1.0f + EXP2F(Bb * xg)), Cc);
        // gather the quad: i,f,g~,o to all 4 lanes
        float gi = dpp_qperm<QP_B0>(r);
        float gf = dpp_qperm<QP_B1>(r);
        float gg = dpp_qperm<QP_B2>(r);
        float go = dpp_qperm<QP_B3>(r);
        c = fmaf(gf, c, gi * gg);  // uniform within quad
        float th = fmaf(2.0f, RCPF(1.0f + EXP2F(-2.f * L2E * c)), -1.0f);
        float h = go * th;
        if (q == 0) {
            int trow = d ? (N_SENT - s) : s;
            L[(size_t)trow * 256 + d * HID + u] = h;
            _Float16 hf = (_Float16)h;
            hb[(s + 1) & 1][u] = __builtin_bit_cast(unsigned short, hf);
        }
        p = p1; p1 = p2;
        LDS_BARRIER();
    }
}

// scores[i][j] = (i==j) ? -1e30 : b2 + sum_k w2[k]*tanh(Ap[i][k] + Bm[j][k])
__global__ __launch_bounds__(256) void scores_k(
    const float* __restrict__ Ap,   // [769][128]
    const float* __restrict__ Bm,   // [768][128]
    const float* __restrict__ w2,
    const float* __restrict__ b2,
    float* __restrict__ out)        // [769][768]
{
    __shared__ __align__(16) float Asl[32][132];
    __shared__ __align__(16) float Bsl[32][132];
    __shared__ __align__(16) float w2s[F_DIM];
    int tid = threadIdx.x;
    int i0 = blockIdx.x * 32, j0 = blockIdx.y * 32;

    for (int e = tid; e < 1024; e += 256) {
        int r = e >> 5;
        int qq = (e & 31) << 2;
        float4 av = (i0 + r < T_SEQ)
                        ? *(const float4*)(Ap + (size_t)(i0 + r) * F_DIM + qq)
                        : make_float4(0.f, 0.f, 0.f, 0.f);
        *(float4*)&Asl[r][qq] = av;
        float4 bv = *(const float4*)(Bm + (size_t)(j0 + r) * F_DIM + qq);
        *(float4*)&Bsl[r][qq] = bv;
    }
    if (tid < 32) {
        *(float4*)&w2s[tid * 4] = *(const float4*)(w2 + tid * 4);
    }
    __syncthreads();

    int tx = tid & 15, ty = tid >> 4;
    float s[2][2] = {};
    #pragma unroll 8
    for (int k4 = 0; k4 < F_DIM; k4 += 4) {
        float4 a0 = *(const float4*)&Asl[ty * 2][k4];
        float4 a1 = *(const float4*)&Asl[ty * 2 + 1][k4];
        float4 b0 = *(const float4*)&Bsl[tx * 2][k4];
        float4 b1v = *(const float4*)&Bsl[tx * 2 + 1][k4];
        float4 wv = *(const float4*)&w2s[k4];
        float aa[2][4] = {{a0.x, a0.y, a0.z, a0.w}, {a1.x, a1.y, a1.z, a1.w}};
        float bb[2][4] = {{b0.x, b0.y, b0.z, b0.w}, {b1v.x, b1v.y, b1v.z, b1v.w}};
        float ww[4] = {wv.x, wv.y, wv.z, wv.w};
        #pragma unroll
        for (int kk = 0; kk < 4; ++kk)
            #pragma unroll
            for (int ii = 0; ii < 2; ++ii)
                #pragma unroll
                for (int jj = 0; jj < 2; ++jj)
                    s[ii][jj] = fmaf(ww[kk], tanh_f(aa[ii][kk] + bb[jj][kk]), s[ii][jj]);
    }

    float bb2 = b2[0];
    #pragma unroll
    for (int ii = 0; ii < 2; ++ii) {
        int i = i0 + ty * 2 + ii;
        if (i < T_SEQ) {
            #pragma unroll
            for (int jj = 0; jj < 2; ++jj) {
                int j = j0 + tx * 2 + jj;
                out[(size_t)i * N_SENT + j] =
                    (i == j) ? -1.0e30f : (s[ii][jj] + bb2);
            }
        }
    }
}

extern "C" void kernel_launch(void* const* d_in, const int* in_sizes, int n_in,
                              void* d_out, int out_size, void* d_ws, size_t ws_size,
                              hipStream_t stream) {
    const float* sent = (const float*)d_in[0];
    const float* root = (const float*)d_in[2];
    const float* Wih  = (const float*)d_in[3];  // (2,2,512,256)
    const float* Whh  = (const float*)d_in[4];  // (2,2,512,128)
    const float* bih  = (const float*)d_in[5];  // (2,2,512)
    const float* bhh  = (const float*)d_in[6];  // (2,2,512)
    const float* W1   = (const float*)d_in[7];  // (128,512)
    const float* b1   = (const float*)d_in[8];  // (128)
    const float* w2   = (const float*)d_in[9];  // (128)
    const float* b2   = (const float*)d_in[10]; // (1)
    float* out = (float*)d_out;
    float* ws = (float*)d_ws;

    float* x   = ws;                       // 769*256
    float* pre = x + T_SEQ * E_IN;         // 2*769*512
    float* L0  = pre + 2 * T_SEQ * G4;     // 769*256
    float* L1  = L0 + T_SEQ * 256;         // 769*256
    float* Ap  = L1 + T_SEQ * 256;         // 769*128
    float* Bm  = Ap + T_SEQ * F_DIM;       // 768*128

    build_x<<<T_SEQ, E_IN, 0, stream>>>(sent, root, x);

    dim3 b256(256);
    dim3 gpre(13, 8);
    gemm_nt<<<gpre, b256, 0, stream>>>(x, E_IN, T_SEQ, 0,
                                       Wih, E_IN, bih, bhh, pre, G4, E_IN);
    gemm_nt<<<gpre, b256, 0, stream>>>(x, E_IN, T_SEQ, 1,
                                       Wih + (size_t)G4 * E_IN, E_IN,
                                       bih + G4, bhh + G4,
                                       pre + (size_t)T_SEQ * G4, G4, E_IN);
    lstm_layer<<<2, 512, 0, stream>>>(pre, Whh, L0);

    gemm_nt<<<gpre, b256, 0, stream>>>(L0, 256, T_SEQ, 0,
                                       Wih + (size_t)2 * G4 * E_IN, 256,
                                       bih + 2 * G4, bhh + 2 * G4, pre, G4, 256);
    gemm_nt<<<gpre, b256, 0, stream>>>(L0, 256, T_SEQ, 1,
                                       Wih + (size_t)3 * G4 * E_IN, 256,
                                       bih + 3 * G4, bhh + 3 * G4,
                                       pre + (size_t)T_SEQ * G4, G4, 256);
    lstm_layer<<<2, 512, 0, stream>>>(pre, Whh + (size_t)2 * G4 * HID, L1);

    gemm_nt<<<dim3(13, 2), b256, 0, stream>>>(L1, 256, T_SEQ, 0,
                                              W1, 512, b1, nullptr, Ap, F_DIM, 256);
    gemm_nt<<<dim3(12, 2), b256, 0, stream>>>(L1, 256, N_SENT, 0,
                                              W1 + 256, 512, nullptr, nullptr, Bm, F_DIM, 256);

    scores_k<<<dim3(25, 24), b256, 0, stream>>>(Ap, Bm, w2, b2, out);
}